// Round 16
// baseline (97.777 us; speedup 1.0000x reference)
//
#include <hip/hip_runtime.h>

#define TT    512
#define WW    257
#define HWSZ  (WW*WW)          // 66049
#define IMG2  (2*HWSZ)         // time stride in `output` (2 channels)
#define SCALE 3.5682482323055424f   // DT^-0.5 / gamma(1.5)
#define KD    163.84f               // KAPPA / DX^2

typedef short bf16x8 __attribute__((ext_vector_type(8)));
typedef short bf16x4 __attribute__((ext_vector_type(4)));
typedef float f32x4  __attribute__((ext_vector_type(4)));
typedef unsigned int u32x4 __attribute__((ext_vector_type(4)));

__device__ __forceinline__ float wf(int j) {
    return sqrtf((float)(j + 1)) - sqrtf((float)j);
}
__device__ __forceinline__ float mcoef(int i, int k) {
    if (i == 0 || k > i) return 0.f;
    if (k == i) return 1.f;
    if (k == 0) return -wf(i - 1);
    int d = i - k;
    return wf(d) - wf(d - 1);
}
__device__ __forceinline__ unsigned short f2b(float f) {
    unsigned u = __float_as_uint(f);
    return (unsigned short)((u + 0x7FFFu + ((u >> 16) & 1u)) >> 16);
}
__device__ __forceinline__ float b2f(unsigned short h) {
    return __uint_as_float(((unsigned)h) << 16);
}

// ---- kernel 1: M as bf16 [512][512] (L2-resident); also zeroes d_out
__global__ __launch_bounds__(256)
void build_m(unsigned short* __restrict__ M, float* __restrict__ d_out) {
    int i = blockIdx.x;
    if (i == 0 && threadIdx.x == 0) *d_out = 0.f;
    for (int k = threadIdx.x; k < TT; k += 256)
        M[i * TT + k] = f2b(mcoef(i, k));
}

// ---- fused Y=2, SOFTWARE-PIPELINED: interval k = { MFMA(k) || STAGE(k+1) }.
// grid 512, 8 waves. Wave w: i-tiles [32w,32w+32) and [480-32w,512-32w).
__global__ __launch_bounds__(512, 2)
void fused(const float* __restrict__ uin, const float* __restrict__ f1p,
           const float* __restrict__ lapk, const unsigned short* __restrict__ Mb,
           float* __restrict__ d_out)
{
    __shared__ unsigned short uS[2][128][64];   // [buf][px'][t-local] swizzled 16B segs
    __shared__ unsigned short sS[2][64][136];   // [buf][t-local][px' + pad]
    __shared__ float red[8];

    const int tid  = threadIdx.x;
    const int w    = tid >> 6;
    const int lane = tid & 63;
    const int lr   = lane & 15;
    const int lg   = lane >> 4;

    const int bid = blockIdx.x;                 // 512
    const int wg  = (bid & 7) * 64 + (bid >> 3);
    const int xt  = wg >> 7;                    // 0..3
    const int ypb = wg & 127;                   // 0..127
    const int Y0  = 1 + 2 * ypb;
    const int c0  = xt * 64;
    const bool validB = (Y0 + 1) <= 255;

    const float ka = lapk[0], kb = lapk[1], kc = lapk[4];

    f32x4 acc0[8][2], acc1[8][2];
    #pragma unroll
    for (int a = 0; a < 8; ++a) {
        acc0[a][0] = (f32x4)0.f; acc0[a][1] = (f32x4)0.f;
        acc1[a][0] = (f32x4)0.f; acc1[a][1] = (f32x4)0.f;
    }

    const bool pad = (c0 + lane) == 255;
    const int  i00 = 32 * w;
    const int  i01 = 480 - 32 * w;
    const int  ec0 = w >> 1;
    const int  ec1 = (15 - w) >> 1;
    float lsum = 0.f;

    float a0[8], a1[8], a2[8], a3[8], fA[8], fB[8], ee;
    const int tl = lane >> 3, code = lane & 7, side = code >> 2, rj = code & 3;
    const size_t geoff = (size_t)tl * IMG2 + (size_t)(Y0 - 1 + rj) * WW
                       + (side ? c0 + 65 : c0);

    bf16x8 m0a[2], m0b[2], m1a[2], m1b[2];

    auto LOADR = [&](int c) {
        const int tb = 64 * c + 8 * w;
        const float* pu = uin + (size_t)tb * IMG2 + (size_t)(Y0 - 1) * WW + (c0 + 1) + lane;
        const float* pf = f1p + (size_t)tb * HWSZ + (size_t)Y0 * WW + (c0 + 1) + lane;
        #pragma unroll
        for (int rr = 0; rr < 8; ++rr) {
            const float* qu = pu + (size_t)rr * IMG2;
            a0[rr] = qu[0]; a1[rr] = qu[WW]; a2[rr] = qu[2 * WW]; a3[rr] = qu[3 * WW];
            fA[rr] = pf[(size_t)rr * HWSZ];
            fB[rr] = pf[(size_t)rr * HWSZ + WW];
        }
        ee = uin[(size_t)tb * IMG2 + geoff];
    };

    auto MLOAD = [&](int k) {
        #pragma unroll
        for (int sub = 0; sub < 2; ++sub) {
            const int s_ = 2 * k + sub;
            if (s_ <= w) {
                const unsigned short* mp0 = Mb + (size_t)(i00 + lr) * TT + 32 * s_ + 8 * lg;
                m0a[sub] = *(const bf16x8*)mp0; m0b[sub] = *(const bf16x8*)(mp0 + 16 * TT);
            }
            if (s_ <= 15 - w) {
                const unsigned short* mp1 = Mb + (size_t)(i01 + lr) * TT + 32 * s_ + 8 * lg;
                m1a[sub] = *(const bf16x8*)mp1; m1b[sub] = *(const bf16x8*)(mp1 + 16 * TT);
            }
        }
    };

    auto STAGE = [&](int b) {
        float e1  = __shfl(ee, lane + 1, 64);
        float e2  = __shfl(ee, lane + 2, 64);
        float QeX = fmaf(ka, ee + e2, kb * e1);
        u32x4 upA, upB;
        #pragma unroll
        for (int rr = 0; rr < 8; ++rr) {
            float PA = a0[rr] + a2[rr];
            float QA = fmaf(ka, PA, kb * a1[rr]);
            float RA = fmaf(kb, PA, kc * a1[rr]);
            float PB = a1[rr] + a3[rr];
            float QB = fmaf(ka, PB, kb * a2[rr]);
            float RB = fmaf(kb, PB, kc * a2[rr]);
            float qmA = __shfl(QA, lane - 1, 64), qpA = __shfl(QA, lane + 1, 64);
            float qmB = __shfl(QB, lane - 1, 64), qpB = __shfl(QB, lane + 1, 64);
            float eA0 = __shfl(QeX, 8 * rr,     64), eA1 = __shfl(QeX, 8 * rr + 4, 64);
            float eB0 = __shfl(QeX, 8 * rr + 1, 64), eB1 = __shfl(QeX, 8 * rr + 5, 64);
            if (lane == 0)  { qmA = eA0; qmB = eB0; }
            if (lane == 63) { qpA = eA1; qpB = eB1; }
            float lapA = qmA + qpA + RA;
            float lapB = qmB + qpB + RB;
            float sA  = a1[rr] - fmaf(KD, lapA, fA[rr]);
            float sB_ = a2[rr] - fmaf(KD, lapB, fB[rr]);
            unsigned short uAv = pad ? (unsigned short)0 : f2b(a1[rr]);
            unsigned short sAv = pad ? (unsigned short)0 : f2b(sA);
            unsigned short uBv = (pad || !validB) ? (unsigned short)0 : f2b(a2[rr]);
            unsigned short sBv = (pad || !validB) ? (unsigned short)0 : f2b(sB_);
            sS[b][8 * w + rr][lane]      = sAv;
            sS[b][8 * w + rr][64 + lane] = sBv;
            if (rr & 1) { upA[rr >> 1] |= ((unsigned)uAv) << 16; upB[rr >> 1] |= ((unsigned)uBv) << 16; }
            else        { upA[rr >> 1]  = (unsigned)uAv;         upB[rr >> 1]  = (unsigned)uBv; }
        }
        *(u32x4*)&uS[b][lane]     [(w ^ (lane & 7)) * 8] = upA;
        *(u32x4*)&uS[b][64 + lane][(w ^ (lane & 7)) * 8] = upB;
    };

    auto EPI = [&](f32x4 (&acc)[8][2], int b, int lbase) {
        #pragma unroll
        for (int mi = 0; mi < 8; ++mi)
            #pragma unroll
            for (int nj = 0; nj < 2; ++nj) {
                bf16x4 sv = *(const bf16x4*)&sS[b][lbase + 16 * nj + lr][16 * mi + 4 * lg];
                #pragma unroll
                for (int r = 0; r < 4; ++r) {
                    float res = SCALE * acc[mi][nj][r] + b2f((unsigned short)sv[r]);
                    lsum += res * res;
                }
            }
    };

    // ---- prologue: PF(0) -> STAGE(0) into buf0; M(0); PF(1); publish.
    LOADR(0);
    MLOAD(0);
    STAGE(0);
    LOADR(1);
    __builtin_amdgcn_sched_barrier(0);
    asm volatile("s_waitcnt lgkmcnt(0)");
    __builtin_amdgcn_sched_barrier(0);
    __builtin_amdgcn_s_barrier();
    __builtin_amdgcn_sched_barrier(0);

    // ---- pipelined main loop: interval k = MFMA(k) || STAGE(k+1), 1 barrier.
    for (int k = 0; k < 8; ++k) {
        const int b = k & 1;

        // MFMA(k): uses M loaded last interval (older than the in-flight PF burst)
        #pragma unroll
        for (int sub = 0; sub < 2; ++sub) {
            const int s_ = 2 * k + sub;
            if (s_ <= w) {
                #pragma unroll
                for (int mi = 0; mi < 8; ++mi) {
                    bf16x8 a = *(const bf16x8*)&uS[b][16 * mi + lr][(((4 * sub + lg) ^ (lr & 7))) * 8];
                    acc0[mi][0] = __builtin_amdgcn_mfma_f32_16x16x32_bf16(a, m0a[sub], acc0[mi][0], 0, 0, 0);
                    acc0[mi][1] = __builtin_amdgcn_mfma_f32_16x16x32_bf16(a, m0b[sub], acc0[mi][1], 0, 0, 0);
                }
            }
            if (s_ <= 15 - w) {
                #pragma unroll
                for (int mi = 0; mi < 8; ++mi) {
                    bf16x8 a = *(const bf16x8*)&uS[b][16 * mi + lr][(((4 * sub + lg) ^ (lr & 7))) * 8];
                    acc1[mi][0] = __builtin_amdgcn_mfma_f32_16x16x32_bf16(a, m1a[sub], acc1[mi][0], 0, 0, 0);
                    acc1[mi][1] = __builtin_amdgcn_mfma_f32_16x16x32_bf16(a, m1b[sub], acc1[mi][1], 0, 0, 0);
                }
            }
        }
        if (k == ec0) EPI(acc0, b, 32 * (w & 1));
        if (k == ec1) EPI(acc1, b, 32 * ((w + 1) & 1));

        if (k < 7) {
            STAGE(b ^ 1);              // chunk k+1 (PF loaded last interval; co-runs with MFMA)
            MLOAD(k + 1);              // WAR reuse of m regs after MFMA(k) consumed them
            if (k < 6) LOADR(k + 2);   // burst lands during interval k+1

            __builtin_amdgcn_sched_barrier(0);
            asm volatile("s_waitcnt lgkmcnt(0)");
            __builtin_amdgcn_sched_barrier(0);
            __builtin_amdgcn_s_barrier();
            __builtin_amdgcn_sched_barrier(0);
        }
    }

    // ---- reduce: wave shfl -> LDS -> one atomic per block
    #pragma unroll
    for (int off = 32; off > 0; off >>= 1)
        lsum += __shfl_down(lsum, off, 64);
    if (lane == 0) red[w] = lsum;
    __syncthreads();
    if (tid == 0) {
        float tot = 0.f;
        #pragma unroll
        for (int q = 0; q < 8; ++q) tot += red[q];
        atomicAdd(d_out, tot * (1.0f / 33292800.0f));
    }
}

extern "C" void kernel_launch(void* const* d_in, const int* in_sizes, int n_in,
                              void* d_out, int out_size, void* d_ws, size_t ws_size,
                              hipStream_t stream)
{
    const float* uin  = (const float*)d_in[0];
    const float* f1   = (const float*)d_in[1];
    const float* lapk = (const float*)d_in[2];
    float* out = (float*)d_out;

    unsigned short* Mb = (unsigned short*)d_ws;   // 512 KB

    build_m<<<dim3(TT), 256, 0, stream>>>(Mb, out);
    fused<<<dim3(512), 512, 0, stream>>>(uin, f1, lapk, Mb, out);
}